// Round 1
// baseline (629.295 us; speedup 1.0000x reference)
//
#include <hip/hip_runtime.h>
#include <float.h>
#include <stdint.h>

// MFMA fragment types (per guide: 8 bf16 in 4 VGPRs as short8; 4 fp32 acc)
typedef __attribute__((ext_vector_type(8))) short bf16x8;
typedef __attribute__((ext_vector_type(4))) float f32x4;

__device__ __forceinline__ unsigned short f2bf(float f) {
  unsigned u = __builtin_bit_cast(unsigned, f);
  u += 0x7fffu + ((u >> 16) & 1u);
  return (unsigned short)(u >> 16);
}

// ---------------------------------------------------------------------------
// K1a: Wt[o][k] = bf16( sum_c w1[k,c] * w2[c,o] )   (128 x 512 bf16)
// grid 32 x 256
__global__ void k_prep_wt(const float* __restrict__ w1, const float* __restrict__ w2,
                          unsigned short* __restrict__ Wt) {
  int tid = blockIdx.x * 256 + threadIdx.x;
  int o = tid & 127;
  int kc = tid >> 7;  // 0..63
  for (int kk = 0; kk < 8; ++kk) {
    int k = kc * 8 + kk;
    const float* w1r = w1 + k * 256;
    float acc = 0.f;
    for (int c = 0; c < 256; ++c) acc += w1r[c] * w2[c * 128 + o];
    Wt[o * 512 + k] = f2bf(acc);
  }
}

// K1b: dval[o] = sum_c b1[c]*w2[c,o] + b2[o]   (generic odd-odd feat value)
// grid 1 x 128
__global__ void k_prep_dval(const float* __restrict__ b1, const float* __restrict__ w2,
                            const float* __restrict__ b2, float* __restrict__ dval) {
  int o = threadIdx.x;
  float acc = 0.f;
  for (int c = 0; c < 256; ++c) acc += b1[c] * w2[c * 128 + o];
  dval[o] = acc + b2[o];
}

// K1c: wlT[m][k'] = bf16( wl[o*16+cell][m] ), k' = cell*128+o  (1024 x 2048 bf16)
// grid 1024 x 256; lanes read consecutive m (coalesced), 16B store per thread.
__global__ void k_prep_wlt(const float* __restrict__ wl, unsigned short* __restrict__ wlT) {
  int tid = blockIdx.x * 256 + threadIdx.x;
  int m = tid & 1023;
  int chunk = tid >> 10;       // 0..255
  int c = chunk >> 4;          // cell
  int o0 = (chunk & 15) * 8;
  union { unsigned short s[8]; uint4 q; } u;
  for (int i = 0; i < 8; ++i)
    u.s[i] = f2bf(wl[((o0 + i) * 16 + c) * 1024 + m]);
  *(uint4*)&wlT[(size_t)m * 2048 + c * 128 + o0] = u.q;
}

// ---------------------------------------------------------------------------
// K2: D[(n*4+pq)][o] = sum_k x[n,k,pos(pq)] * W[k][o] + dval[o]
// GEMM M=32768 (rows = 4 per n), K=512, N=128, bf16 MFMA, gathered A staging.
// grid 256 blocks x 256 threads; block tile 128(M) x 128(N), BK=64.
__global__ __launch_bounds__(256) void k_dgemm(
    const float* __restrict__ x,            // (8192, 512, 16) f32
    const unsigned short* __restrict__ Wt,  // (128, 512) bf16
    const float* __restrict__ dval,
    float* __restrict__ D)                  // (32768, 128) f32
{
  __shared__ __align__(16) unsigned short As[128 * 64];
  __shared__ __align__(16) unsigned short Bs[128 * 64];
  const int t = threadIdx.x;
  const int bm = blockIdx.x;     // 0..255
  const int n0 = bm * 32;
  const int w = t >> 6, lane = t & 63;
  const int wm = (w >> 1) * 64, wn = (w & 1) * 64;
  const int lrow = lane & 15, lk = (lane >> 4) * 8;

  f32x4 acc[4][4];
  const f32x4 z = {0.f, 0.f, 0.f, 0.f};
  for (int i = 0; i < 4; ++i) for (int j = 0; j < 4; ++j) acc[i][j] = z;

  for (int k0 = 0; k0 < 512; k0 += 64) {
    // stage B: Wt rows (contiguous bf16), 2 threads per row x 64B
    {
      int row = t >> 1, half = (t & 1) * 32;
      const unsigned short* gp = Wt + row * 512 + k0 + half;
      uint4 q0 = *(const uint4*)(gp + 0);
      uint4 q1 = *(const uint4*)(gp + 8);
      uint4 q2 = *(const uint4*)(gp + 16);
      uint4 q3 = *(const uint4*)(gp + 24);
      unsigned short* sp = Bs + row * 64 + half;
      *(uint4*)(sp + 0)  = q0;
      *(uint4*)(sp + 8)  = q1;
      *(uint4*)(sp + 16) = q2;
      *(uint4*)(sp + 24) = q3;
    }
    // stage A: gather x[n, k, {5,6,9,10}] -> 4 rows (pq) at column k
    for (int s = 0; s < 8; ++s) {
      int li = s * 256 + t;
      int nl = li >> 6;   // 0..31
      int k = li & 63;
      const float* gp = x + (size_t)(n0 + nl) * 8192 + (size_t)(k0 + k) * 16;
      float f5 = gp[5], f6 = gp[6], f9 = gp[9], f10 = gp[10];
      unsigned short* sp = As + (nl * 4) * 64 + k;
      sp[0]   = f2bf(f5);
      sp[64]  = f2bf(f6);
      sp[128] = f2bf(f9);
      sp[192] = f2bf(f10);
    }
    __syncthreads();
    for (int kk = 0; kk < 64; kk += 32) {
      bf16x8 a[4], b[4];
      for (int i = 0; i < 4; ++i)
        a[i] = *(const bf16x8*)&As[(wm + i * 16 + lrow) * 64 + kk + lk];
      for (int j = 0; j < 4; ++j)
        b[j] = *(const bf16x8*)&Bs[(wn + j * 16 + lrow) * 64 + kk + lk];
      for (int i = 0; i < 4; ++i)
        for (int j = 0; j < 4; ++j)
          acc[i][j] = __builtin_amdgcn_mfma_f32_16x16x32_bf16(a[i], b[j], acc[i][j], 0, 0, 0);
    }
    __syncthreads();
  }
  // epilogue: + dval, store f32
  const int rbase = bm * 128 + wm + (lane >> 4) * 4;
  for (int j = 0; j < 4; ++j) {
    int col = wn + j * 16 + (lane & 15);
    float dv = dval[col];
    for (int i = 0; i < 4; ++i) {
      for (int r = 0; r < 4; ++r) {
        int row = rbase + i * 16 + r;
        D[(size_t)row * 128 + col] = acc[i][j][r] + dv;
      }
    }
  }
}

// ---------------------------------------------------------------------------
// K3: pooling via per-cell candidate masks.
// feat[n,o,y,x] = b2[o] (y or x even) | dval[o] (odd-odd generic)
//              | D[n,pq,o] at (y,x) in {3,7}x{3,7}, pq = (y==7)*2 + (x==7)
// pooled[n*2048 + cell*128 + o]  (K-permuted layout, matches wlT)
// grid 4096 x 256 (2 n per block)
__device__ __forceinline__ int cellmask(int cat, int y0, int x0, int i, int j) {
  int ys[3], xs[3];
  int ny, nx;
  switch (cat) {
    case 0: ys[0] = y0 + i; ny = 1; xs[0] = x0 + j; nx = 1; break;
    case 1: ys[0] = y0 + 2 * i; ys[1] = ys[0] + 1; ny = 2;
            xs[0] = x0 + 2 * j; xs[1] = xs[0] + 1; nx = 2; break;
    case 2: ys[0] = y0 + i; ny = 1;
            xs[0] = x0 + 2 * j; xs[1] = xs[0] + 1; nx = 2; break;
    case 3: if (i == 0) { ys[0] = y0; ny = 1; }
            else if (i == 3) { ys[0] = y0 + 5; ny = 1; }
            else { ys[0] = y0 + 2 * i - 1; ys[1] = y0 + 2 * i; ny = 2; }
            xs[0] = x0 + 2 * j; xs[1] = xs[0] + 1; nx = 2; break;
    default: ys[0] = 1 + 2 * i; ys[1] = 2 + 2 * i; ys[2] = 3 + 2 * i; ny = 3;
             xs[0] = 1 + 2 * j; xs[1] = 2 + 2 * j; xs[2] = 3 + 2 * j; nx = 3; break;
  }
  int m = 0;
  for (int a = 0; a < ny; ++a)
    for (int b = 0; b < nx; ++b) {
      int y = ys[a], xx = xs[b];
      if ((y & 1) && (xx & 1)) {
        if ((y == 3 || y == 7) && (xx == 3 || xx == 7))
          m |= 1 << (2 + ((y == 7) ? 2 : 0) + ((xx == 7) ? 1 : 0));
        else
          m |= 2;
      } else {
        m |= 1;
      }
    }
  return m;
}

__global__ __launch_bounds__(256) void k_pool(
    const int* __restrict__ rois, const float* __restrict__ D,
    const float* __restrict__ dval, const float* __restrict__ b2,
    unsigned short* __restrict__ pooled)
{
  const int t = threadIdx.x;
  const int nl = t >> 7, o = t & 127;
  const int n = blockIdx.x * 2 + nl;
  const int* rr = rois + n * 4;
  int y0 = rr[0], x0 = rr[1], y1 = rr[2], x1 = rr[3];
  bool inb = ((unsigned)y0 < 11u) && ((unsigned)x0 < 11u) &&
             ((unsigned)y1 < 11u) && ((unsigned)x1 < 11u);
  int h = y1 - y0, ww = x1 - x0;
  int cat;
  if (inb && h == 4 && ww == 4) cat = 0;
  else if (inb && h == 8 && ww == 8) cat = 1;
  else if (inb && h == 4 && ww == 8) cat = 2;
  else if (inb && h == 6 && ww == 8) cat = 3;
  else { cat = 4; y0 = 1; x0 = 1; }

  float cand[6];
  cand[0] = b2[o];
  cand[1] = dval[o];
  const float* Dp = D + (size_t)n * 512 + o;
  cand[2] = Dp[0];
  cand[3] = Dp[128];
  cand[4] = Dp[256];
  cand[5] = Dp[384];

  unsigned short* op = pooled + (size_t)n * 2048 + o;
  for (int cell = 0; cell < 16; ++cell) {
    int i = cell >> 2, j = cell & 3;
    int mask = cellmask(cat, y0, x0, i, j);
    float v = -FLT_MAX;
    for (int b = 0; b < 6; ++b)
      if (mask & (1 << b)) v = fmaxf(v, cand[b]);
    op[cell * 128] = f2bf(v);
  }
}

// ---------------------------------------------------------------------------
// K4: out = leaky( pooled(8192x2048 bf16) @ wlT(1024x2048 bf16)^T + bl )
// grid (64, 8) x 256 threads; block tile 128x128, BK=32 (m97-style NT gemm).
__global__ __launch_bounds__(256) void k_gemm(
    const unsigned short* __restrict__ A,   // (8192, 2048) bf16
    const unsigned short* __restrict__ B,   // (1024, 2048) bf16 (N-major, K-contig)
    const float* __restrict__ bias,         // (1024)
    float* __restrict__ C)                  // (8192, 1024) f32
{
  __shared__ __align__(16) unsigned short As[128 * 32];
  __shared__ __align__(16) unsigned short Bs[128 * 32];
  const int t = threadIdx.x;
  const int bm = blockIdx.x, bn = blockIdx.y;
  const int r0 = bm * 128, c0 = bn * 128;
  const int w = t >> 6, lane = t & 63;
  const int wm = (w >> 1) * 64, wn = (w & 1) * 64;
  const int lrow = lane & 15, lk = (lane >> 4) * 8;

  f32x4 acc[4][4];
  const f32x4 z = {0.f, 0.f, 0.f, 0.f};
  for (int i = 0; i < 4; ++i) for (int j = 0; j < 4; ++j) acc[i][j] = z;

  const int srow = t >> 1, scol = (t & 1) * 16;  // staging: 2 threads/row x 32B
  const size_t Abase = (size_t)(r0 + srow) * 2048 + scol;
  const size_t Bbase = (size_t)(c0 + srow) * 2048 + scol;
  unsigned short* spA = As + srow * 32 + scol;
  unsigned short* spB = Bs + srow * 32 + scol;

  for (int k0 = 0; k0 < 2048; k0 += 32) {
    uint4 a0 = *(const uint4*)(A + Abase + k0);
    uint4 a1 = *(const uint4*)(A + Abase + k0 + 8);
    uint4 b0 = *(const uint4*)(B + Bbase + k0);
    uint4 b1 = *(const uint4*)(B + Bbase + k0 + 8);
    *(uint4*)(spA + 0) = a0;
    *(uint4*)(spA + 8) = a1;
    *(uint4*)(spB + 0) = b0;
    *(uint4*)(spB + 8) = b1;
    __syncthreads();
    bf16x8 a[4], b[4];
    for (int i = 0; i < 4; ++i)
      a[i] = *(const bf16x8*)&As[(wm + i * 16 + lrow) * 32 + lk];
    for (int j = 0; j < 4; ++j)
      b[j] = *(const bf16x8*)&Bs[(wn + j * 16 + lrow) * 32 + lk];
    for (int i = 0; i < 4; ++i)
      for (int j = 0; j < 4; ++j)
        acc[i][j] = __builtin_amdgcn_mfma_f32_16x16x32_bf16(a[i], b[j], acc[i][j], 0, 0, 0);
    __syncthreads();
  }

  const int rbase = r0 + wm + (lane >> 4) * 4;
  for (int j = 0; j < 4; ++j) {
    int col = c0 + wn + j * 16 + (lane & 15);
    float bv = bias[col];
    for (int i = 0; i < 4; ++i) {
      for (int r = 0; r < 4; ++r) {
        int row = rbase + i * 16 + r;
        float v = acc[i][j][r] + bv;
        C[(size_t)row * 1024 + col] = v > 0.f ? v : 0.01f * v;
      }
    }
  }
}

// ---------------------------------------------------------------------------
extern "C" void kernel_launch(void* const* d_in, const int* in_sizes, int n_in,
                              void* d_out, int out_size, void* d_ws, size_t ws_size,
                              hipStream_t stream) {
  const float* base_feat = (const float*)d_in[0];  // (32,256,512,4,4)
  const int*   rois      = (const int*)d_in[1];    // (8192,4)
  const float* w1        = (const float*)d_in[2];  // (512,256)
  const float* b1        = (const float*)d_in[3];  // (256)
  const float* w2        = (const float*)d_in[4];  // (256,128)
  const float* b2        = (const float*)d_in[5];  // (128)
  const float* wl        = (const float*)d_in[6];  // (2048,1024)
  const float* bl        = (const float*)d_in[7];  // (1024)
  float* out = (float*)d_out;                      // (8192,1024)

  char* ws = (char*)d_ws;
  // ws layout (bytes):
  //   Wt    bf16 128x512  @ 0         (131072)
  //   dval  f32  128      @ 131072    (512)
  //   Dbuf  f32  32768x128@ 131584    (16777216)
  //   pooled bf16 8192x2048 @ 16908800 (33554432)
  //   wlT   bf16 1024x2048 @ 50463232 (4194304)   total 54657536
  unsigned short* Wt   = (unsigned short*)(ws + 0);
  float*          dval = (float*)(ws + 131072);
  float*          Dbuf = (float*)(ws + 131584);
  unsigned short* pooled = (unsigned short*)(ws + 16908800);
  unsigned short* wlT  = (unsigned short*)(ws + 50463232);

  k_prep_wt  <<<dim3(32),   dim3(256), 0, stream>>>(w1, w2, Wt);
  k_prep_dval<<<dim3(1),    dim3(128), 0, stream>>>(b1, w2, b2, dval);
  k_prep_wlt <<<dim3(1024), dim3(256), 0, stream>>>(wl, wlT);
  k_dgemm    <<<dim3(256),  dim3(256), 0, stream>>>(base_feat, Wt, dval, Dbuf);
  k_pool     <<<dim3(4096), dim3(256), 0, stream>>>(rois, Dbuf, dval, b2, pooled);
  k_gemm     <<<dim3(64, 8), dim3(256), 0, stream>>>(pooled, wlT, bl, out);
}

// Round 2
// 542.324 us; speedup vs baseline: 1.1604x; 1.1604x over previous
//
#include <hip/hip_runtime.h>
#include <float.h>
#include <stdint.h>

typedef __attribute__((ext_vector_type(8))) short bf16x8;
typedef __attribute__((ext_vector_type(4))) float f32x4;

__device__ __forceinline__ unsigned short f2bf(float f) {
  unsigned u = __builtin_bit_cast(unsigned, f);
  u += 0x7fffu + ((u >> 16) & 1u);
  return (unsigned short)(u >> 16);
}

// async global->LDS DMA, 16B per lane; LDS dest = wave-uniform base + lane*16
__device__ __forceinline__ void gl_lds16(const void* g, void* s) {
  __builtin_amdgcn_global_load_lds(
      (const __attribute__((address_space(1))) unsigned int*)(uintptr_t)g,
      (__attribute__((address_space(3))) unsigned int*)(unsigned int)(uintptr_t)s,
      16, 0, 0);
}

// ---------------------------------------------------------------------------
// K1a: Wt[o][k] = bf16( sum_c w1[k,c] * w2[c,o] )   (128 x 512 bf16)
// grid 64 x 256
__global__ void k_prep_wt(const float* __restrict__ w1, const float* __restrict__ w2,
                          unsigned short* __restrict__ Wt) {
  int tid = blockIdx.x * 256 + threadIdx.x;
  int o = tid & 127;
  int kc = tid >> 7;  // 0..127
  for (int kk = 0; kk < 4; ++kk) {
    int k = kc * 4 + kk;
    const float* w1r = w1 + k * 256;
    float a0 = 0.f, a1 = 0.f;
    for (int c = 0; c < 256; c += 2) {
      a0 += w1r[c] * w2[c * 128 + o];
      a1 += w1r[c + 1] * w2[(c + 1) * 128 + o];
    }
    Wt[o * 512 + k] = f2bf(a0 + a1);
  }
}

// K1b: dval[o] = sum_c b1[c]*w2[c,o] + b2[o]
__global__ void k_prep_dval(const float* __restrict__ b1, const float* __restrict__ w2,
                            const float* __restrict__ b2, float* __restrict__ dval) {
  int o = threadIdx.x;
  float acc = 0.f;
  for (int c = 0; c < 256; ++c) acc += b1[c] * w2[c * 128 + o];
  dval[o] = acc + b2[o];
}

// K1c: per-roi per-cell candidate masks (6 bits): bit0=b2, bit1=dval,
// bit2..5 = D at (3,3),(3,7),(7,3),(7,7) i.e. pq 0..3.  16 bytes per n.
__device__ __forceinline__ int cellmask(int cat, int y0, int x0, int i, int j) {
  int ys[3], xs[3];
  int ny, nx;
  switch (cat) {
    case 0: ys[0] = y0 + i; ny = 1; xs[0] = x0 + j; nx = 1; break;
    case 1: ys[0] = y0 + 2 * i; ys[1] = ys[0] + 1; ny = 2;
            xs[0] = x0 + 2 * j; xs[1] = xs[0] + 1; nx = 2; break;
    case 2: ys[0] = y0 + i; ny = 1;
            xs[0] = x0 + 2 * j; xs[1] = xs[0] + 1; nx = 2; break;
    case 3: if (i == 0) { ys[0] = y0; ny = 1; }
            else if (i == 3) { ys[0] = y0 + 5; ny = 1; }
            else { ys[0] = y0 + 2 * i - 1; ys[1] = y0 + 2 * i; ny = 2; }
            xs[0] = x0 + 2 * j; xs[1] = xs[0] + 1; nx = 2; break;
    default: ys[0] = 1 + 2 * i; ys[1] = 2 + 2 * i; ys[2] = 3 + 2 * i; ny = 3;
             xs[0] = 1 + 2 * j; xs[1] = 2 + 2 * j; xs[2] = 3 + 2 * j; nx = 3; break;
  }
  int m = 0;
  for (int a = 0; a < ny; ++a)
    for (int b = 0; b < nx; ++b) {
      int y = ys[a], xx = xs[b];
      if ((y & 1) && (xx & 1)) {
        if ((y == 3 || y == 7) && (xx == 3 || xx == 7))
          m |= 1 << (2 + ((y == 7) ? 2 : 0) + ((xx == 7) ? 1 : 0));
        else
          m |= 2;
      } else {
        m |= 1;
      }
    }
  return m;
}

__global__ void k_prep_mask(const int* __restrict__ rois, unsigned char* __restrict__ masks) {
  int n = blockIdx.x * 256 + threadIdx.x;  // grid 32
  const int* rr = rois + n * 4;
  int y0 = rr[0], x0 = rr[1], y1 = rr[2], x1 = rr[3];
  bool inb = ((unsigned)y0 < 11u) && ((unsigned)x0 < 11u) &&
             ((unsigned)y1 < 11u) && ((unsigned)x1 < 11u);
  int h = y1 - y0, ww = x1 - x0;
  int cat;
  if (inb && h == 4 && ww == 4) cat = 0;
  else if (inb && h == 8 && ww == 8) cat = 1;
  else if (inb && h == 4 && ww == 8) cat = 2;
  else if (inb && h == 6 && ww == 8) cat = 3;
  else { cat = 4; y0 = 1; x0 = 1; }
  union { unsigned char b[16]; uint4 q; } u;
  for (int cell = 0; cell < 16; ++cell)
    u.b[cell] = (unsigned char)cellmask(cat, y0, x0, cell >> 2, cell & 3);
  *(uint4*)(masks + n * 16) = u.q;
}

// K1d: wlT[m][k'] = bf16( wl[o*16+cell][m] ), k' = cell*128+o  (1024 x 2048)
// LDS-transposed: both global read and write coalesced. grid 512 x 256.
__global__ __launch_bounds__(256) void k_prep_wlt(const float* __restrict__ wl,
                                                  unsigned short* __restrict__ wlT) {
  __shared__ float tile[64][65];
  int b = blockIdx.x;
  int c = b & 15;           // cell
  int o0 = ((b >> 4) & 1) * 64;
  int m0 = (b >> 5) * 64;   // 0..960
  int t = threadIdx.x;
  int tl = t & 63, th = t >> 6;
  for (int s = 0; s < 16; ++s) {
    int ol = s * 4 + th;
    tile[ol][tl] = wl[((o0 + ol) * 16 + c) * 1024 + m0 + tl];
  }
  __syncthreads();
  for (int s = 0; s < 16; ++s) {
    int ml = s * 4 + th;
    wlT[(size_t)(m0 + ml) * 2048 + c * 128 + o0 + tl] = f2bf(tile[tl][ml]);
  }
}

// ---------------------------------------------------------------------------
// K2+K3 fused: D[(n*4+pq)][o] = sum_k x[n,k,pos(pq)]*W[k][o] + dval, then
// mask-based max-pool straight out of the accumulators -> pooled bf16.
// M-tile 64 (16 n), N=128, BK=64. grid 512 x 256.
__global__ __launch_bounds__(256) void k_dgemm_pool(
    const float* __restrict__ x,            // (8192, 512, 16) f32
    const unsigned short* __restrict__ Wt,  // (128, 512) bf16
    const float* __restrict__ dval, const float* __restrict__ b2,
    const unsigned char* __restrict__ masks,
    unsigned short* __restrict__ pooled)    // (8192, 16, 128) bf16
{
  __shared__ __align__(16) unsigned short As[64 * 64];
  __shared__ __align__(16) unsigned short Bs[128 * 64];
  const int t = threadIdx.x;
  const int bm = blockIdx.x;     // 0..511
  const int n0 = bm * 16;
  const int w = t >> 6, lane = t & 63;
  const int wm = (w >> 1) * 32, wn = (w & 1) * 64;
  const int lrow = lane & 15, lk = (lane >> 4) * 8;

  f32x4 acc[2][4];
  const f32x4 z = {0.f, 0.f, 0.f, 0.f};
  for (int i = 0; i < 2; ++i) for (int j = 0; j < 4; ++j) acc[i][j] = z;

  const int brow = t >> 1, bhalf = (t & 1) * 32;
  for (int k0 = 0; k0 < 512; k0 += 64) {
    // stage B: Wt rows (L2-resident), 2 threads/row x 64B
    {
      const unsigned short* gp = Wt + brow * 512 + k0 + bhalf;
      uint4 q0 = *(const uint4*)(gp + 0);
      uint4 q1 = *(const uint4*)(gp + 8);
      uint4 q2 = *(const uint4*)(gp + 16);
      uint4 q3 = *(const uint4*)(gp + 24);
      unsigned short* sp = Bs + brow * 64 + bhalf;
      *(uint4*)(sp + 0)  = q0;
      *(uint4*)(sp + 8)  = q1;
      *(uint4*)(sp + 16) = q2;
      *(uint4*)(sp + 24) = q3;
    }
    // stage A: gather x[n, k, {5,6,9,10}] via 2x float4, 4 (n,k) per thread
#pragma unroll
    for (int s = 0; s < 4; ++s) {
      int li = s * 256 + t;
      int nl = li >> 6;   // 0..15
      int k = li & 63;
      const float* gp = x + (size_t)(n0 + nl) * 8192 + (size_t)(k0 + k) * 16;
      float4 qa = *(const float4*)(gp + 4);
      float4 qb = *(const float4*)(gp + 8);
      unsigned short* sp = As + nl * 256 + k;
      sp[0]   = f2bf(qa.y);   // pos 5  -> pq0 (3,3)
      sp[64]  = f2bf(qa.z);   // pos 6  -> pq1 (3,7)
      sp[128] = f2bf(qb.y);   // pos 9  -> pq2 (7,3)
      sp[192] = f2bf(qb.z);   // pos 10 -> pq3 (7,7)
    }
    __syncthreads();
#pragma unroll
    for (int kk = 0; kk < 64; kk += 32) {
      bf16x8 a[2], b[4];
      for (int i = 0; i < 2; ++i)
        a[i] = *(const bf16x8*)&As[(wm + i * 16 + lrow) * 64 + kk + lk];
      for (int j = 0; j < 4; ++j)
        b[j] = *(const bf16x8*)&Bs[(wn + j * 16 + lrow) * 64 + kk + lk];
      for (int i = 0; i < 2; ++i)
        for (int j = 0; j < 4; ++j)
          acc[i][j] = __builtin_amdgcn_mfma_f32_16x16x32_bf16(a[i], b[j], acc[i][j], 0, 0, 0);
    }
    __syncthreads();
  }

  // fused pooling epilogue: lane holds all 4 pq of n in acc[i][j][0..3]
  const int lr = lane >> 4, lc = lane & 15;
  for (int i = 0; i < 2; ++i) {
    int n = n0 + (wm >> 2) + i * 4 + lr;
    uint4 mq = *(const uint4*)(masks + n * 16);
    const unsigned char* mb = (const unsigned char*)&mq;
    for (int j = 0; j < 4; ++j) {
      int o = wn + j * 16 + lc;
      float dv = dval[o], bv = b2[o];
      float d0 = acc[i][j][0] + dv, d1 = acc[i][j][1] + dv;
      float d2 = acc[i][j][2] + dv, d3 = acc[i][j][3] + dv;
      unsigned short* op = pooled + (size_t)n * 2048 + o;
#pragma unroll
      for (int cell = 0; cell < 16; ++cell) {
        int m = mb[cell];
        float v = (m & 1) ? bv : -FLT_MAX;
        if (m & 2)  v = fmaxf(v, dv);
        if (m & 4)  v = fmaxf(v, d0);
        if (m & 8)  v = fmaxf(v, d1);
        if (m & 16) v = fmaxf(v, d2);
        if (m & 32) v = fmaxf(v, d3);
        op[cell * 128] = f2bf(v);
      }
    }
  }
}

// ---------------------------------------------------------------------------
// K4: out = leaky( pooled(8192x2048) @ wlT(1024x2048)^T + bl ), m97 structure:
// 128x128 tile, BK=64, global_load_lds width=16. grid (64,8) x 256.
__global__ __launch_bounds__(256) void k_gemm(
    const unsigned short* __restrict__ A,   // (8192, 2048) bf16
    const unsigned short* __restrict__ B,   // (1024, 2048) bf16
    const float* __restrict__ bias,         // (1024)
    float* __restrict__ C)                  // (8192, 1024) f32
{
  __shared__ __align__(16) unsigned short As[128 * 64];
  __shared__ __align__(16) unsigned short Bs[128 * 64];
  const int t = threadIdx.x;
  const int r0 = blockIdx.x * 128, c0 = blockIdx.y * 128;
  const int w = t >> 6, lane = t & 63;
  const int wm = (w >> 1) * 64, wn = (w & 1) * 64;
  const int lrow = lane & 15, lk = (lane >> 4) * 8;

  f32x4 acc[4][4];
  const f32x4 z = {0.f, 0.f, 0.f, 0.f};
  for (int i = 0; i < 4; ++i) for (int j = 0; j < 4; ++j) acc[i][j] = z;

  // wave w stages rows [w*32, w*32+32): 8 rows (1 KB) per DMA call, 4 calls each
  const int srow = lane >> 3;          // 0..7
  const int scol = (lane & 7) * 8;     // bf16 elems
  const unsigned short* Ag = A + (size_t)(r0 + w * 32 + srow) * 2048 + scol;
  const unsigned short* Bg = B + (size_t)(c0 + w * 32 + srow) * 2048 + scol;
  unsigned short* Asb = As + (w * 32) * 64;
  unsigned short* Bsb = Bs + (w * 32) * 64;

  for (int k0 = 0; k0 < 2048; k0 += 64) {
#pragma unroll
    for (int c = 0; c < 4; ++c) {
      gl_lds16(Ag + (size_t)c * 8 * 2048 + k0, Asb + c * 8 * 64);
      gl_lds16(Bg + (size_t)c * 8 * 2048 + k0, Bsb + c * 8 * 64);
    }
    __syncthreads();
#pragma unroll
    for (int kk = 0; kk < 64; kk += 32) {
      bf16x8 a[4], b[4];
      for (int i = 0; i < 4; ++i)
        a[i] = *(const bf16x8*)&As[(wm + i * 16 + lrow) * 64 + kk + lk];
      for (int j = 0; j < 4; ++j)
        b[j] = *(const bf16x8*)&Bs[(wn + j * 16 + lrow) * 64 + kk + lk];
      for (int i = 0; i < 4; ++i)
        for (int j = 0; j < 4; ++j)
          acc[i][j] = __builtin_amdgcn_mfma_f32_16x16x32_bf16(a[i], b[j], acc[i][j], 0, 0, 0);
    }
    __syncthreads();
  }

  const int rbase = r0 + wm + (lane >> 4) * 4;
  for (int j = 0; j < 4; ++j) {
    int col = c0 + wn + j * 16 + (lane & 15);
    float bv = bias[col];
    for (int i = 0; i < 4; ++i) {
      for (int r = 0; r < 4; ++r) {
        int row = rbase + i * 16 + r;
        float v = acc[i][j][r] + bv;
        C[(size_t)row * 1024 + col] = v > 0.f ? v : 0.01f * v;
      }
    }
  }
}

// ---------------------------------------------------------------------------
extern "C" void kernel_launch(void* const* d_in, const int* in_sizes, int n_in,
                              void* d_out, int out_size, void* d_ws, size_t ws_size,
                              hipStream_t stream) {
  const float* base_feat = (const float*)d_in[0];  // (32,256,512,4,4)
  const int*   rois      = (const int*)d_in[1];    // (8192,4)
  const float* w1        = (const float*)d_in[2];  // (512,256)
  const float* b1        = (const float*)d_in[3];  // (256)
  const float* w2        = (const float*)d_in[4];  // (256,128)
  const float* b2        = (const float*)d_in[5];  // (128)
  const float* wl        = (const float*)d_in[6];  // (2048,1024)
  const float* bl        = (const float*)d_in[7];  // (1024)
  float* out = (float*)d_out;                      // (8192,1024)

  char* ws = (char*)d_ws;
  // ws layout (bytes):
  //   Wt     bf16 128x512    @ 0          (131072)
  //   dval   f32  128        @ 131072     (512)
  //   masks  u8   8192x16    @ 131584     (131072)
  //   pooled bf16 8192x2048  @ 262656     (33554432)
  //   wlT    bf16 1024x2048  @ 33817088   (4194304)   total ~38 MB
  unsigned short* Wt     = (unsigned short*)(ws + 0);
  float*          dval   = (float*)(ws + 131072);
  unsigned char*  masks  = (unsigned char*)(ws + 131584);
  unsigned short* pooled = (unsigned short*)(ws + 262656);
  unsigned short* wlT    = (unsigned short*)(ws + 33817088);

  k_prep_wt   <<<dim3(64),   dim3(256), 0, stream>>>(w1, w2, Wt);
  k_prep_dval <<<dim3(1),    dim3(128), 0, stream>>>(b1, w2, b2, dval);
  k_prep_mask <<<dim3(32),   dim3(256), 0, stream>>>(rois, masks);
  k_prep_wlt  <<<dim3(512),  dim3(256), 0, stream>>>(wl, wlT);
  k_dgemm_pool<<<dim3(512),  dim3(256), 0, stream>>>(base_feat, Wt, dval, b2, masks, pooled);
  k_gemm      <<<dim3(64, 8), dim3(256), 0, stream>>>(pooled, wlT, bl, out);
}

// Round 3
// 500.760 us; speedup vs baseline: 1.2567x; 1.0830x over previous
//
#include <hip/hip_runtime.h>
#include <float.h>
#include <stdint.h>

typedef __attribute__((ext_vector_type(8))) short bf16x8;
typedef __attribute__((ext_vector_type(4))) float f32x4;

__device__ __forceinline__ unsigned short f2bf(float f) {
  unsigned u = __builtin_bit_cast(unsigned, f);
  u += 0x7fffu + ((u >> 16) & 1u);
  return (unsigned short)(u >> 16);
}

// async global->LDS DMA, 16B per lane; LDS dest = wave-uniform base + lane*16
__device__ __forceinline__ void gl_lds16(const void* g, void* s) {
  __builtin_amdgcn_global_load_lds(
      (const __attribute__((address_space(1))) unsigned int*)(uintptr_t)g,
      (__attribute__((address_space(3))) unsigned int*)(unsigned int)(uintptr_t)s,
      16, 0, 0);
}

// ---------------------------------------------------------------------------
// per-roi per-cell candidate masks (6 bits): bit0=b2, bit1=dval,
// bit2..5 = D at (3,3),(3,7),(7,3),(7,7) i.e. pq 0..3.
__device__ __forceinline__ int cellmask(int cat, int y0, int x0, int i, int j) {
  int ys[3], xs[3];
  int ny, nx;
  switch (cat) {
    case 0: ys[0] = y0 + i; ny = 1; xs[0] = x0 + j; nx = 1; break;
    case 1: ys[0] = y0 + 2 * i; ys[1] = ys[0] + 1; ny = 2;
            xs[0] = x0 + 2 * j; xs[1] = xs[0] + 1; nx = 2; break;
    case 2: ys[0] = y0 + i; ny = 1;
            xs[0] = x0 + 2 * j; xs[1] = xs[0] + 1; nx = 2; break;
    case 3: if (i == 0) { ys[0] = y0; ny = 1; }
            else if (i == 3) { ys[0] = y0 + 5; ny = 1; }
            else { ys[0] = y0 + 2 * i - 1; ys[1] = y0 + 2 * i; ny = 2; }
            xs[0] = x0 + 2 * j; xs[1] = xs[0] + 1; nx = 2; break;
    default: ys[0] = 1 + 2 * i; ys[1] = 2 + 2 * i; ys[2] = 3 + 2 * i; ny = 3;
             xs[0] = 1 + 2 * j; xs[1] = 2 + 2 * j; xs[2] = 3 + 2 * j; nx = 3; break;
  }
  int m = 0;
  for (int a = 0; a < ny; ++a)
    for (int b = 0; b < nx; ++b) {
      int y = ys[a], xx = xs[b];
      if ((y & 1) && (xx & 1)) {
        if ((y == 3 || y == 7) && (xx == 3 || xx == 7))
          m |= 1 << (2 + ((y == 7) ? 2 : 0) + ((xx == 7) ? 1 : 0));
        else
          m |= 2;
      } else {
        m |= 1;
      }
    }
  return m;
}

// ---------------------------------------------------------------------------
// K1 merged prep. grid 609 x 256:
//   blocks [0,512)   : wlT[m][cell*128+o] = bf16(wl[(o*16+cell)*1024+m])
//   blocks [512,576) : Wt[o][k] = bf16(sum_c w1[k,c]*w2[c,o])
//   blocks [576,608) : roi cell masks
//   block  608       : dval[o] = sum_c b1[c]*w2[c,o] + b2[o]
__global__ __launch_bounds__(256) void k_prep(
    const float* __restrict__ w1, const float* __restrict__ b1,
    const float* __restrict__ w2, const float* __restrict__ b2,
    const float* __restrict__ wl, const int* __restrict__ rois,
    unsigned short* __restrict__ Wt, float* __restrict__ dval,
    unsigned char* __restrict__ masks, unsigned short* __restrict__ wlT)
{
  __shared__ float tile[64][65];
  const int blk = blockIdx.x;
  const int t = threadIdx.x;
  if (blk < 512) {
    // wlT transpose (LDS): both global read and write coalesced
    int c = blk & 15;           // cell
    int o0 = ((blk >> 4) & 1) * 64;
    int m0 = (blk >> 5) * 64;   // 0..960
    int tl = t & 63, th = t >> 6;
    for (int s = 0; s < 16; ++s) {
      int ol = s * 4 + th;
      tile[ol][tl] = wl[((o0 + ol) * 16 + c) * 1024 + m0 + tl];
    }
    __syncthreads();
    for (int s = 0; s < 16; ++s) {
      int ml = s * 4 + th;
      wlT[(size_t)(m0 + ml) * 2048 + c * 128 + o0 + tl] = f2bf(tile[tl][ml]);
    }
  } else if (blk < 576) {
    int tid = (blk - 512) * 256 + t;
    int o = tid & 127;
    int kc = tid >> 7;  // 0..127
    for (int kk = 0; kk < 4; ++kk) {
      int k = kc * 4 + kk;
      const float* w1r = w1 + k * 256;
      float a0 = 0.f, a1 = 0.f;
      for (int c = 0; c < 256; c += 2) {
        a0 += w1r[c] * w2[c * 128 + o];
        a1 += w1r[c + 1] * w2[(c + 1) * 128 + o];
      }
      Wt[o * 512 + k] = f2bf(a0 + a1);
    }
  } else if (blk < 608) {
    int n = (blk - 576) * 256 + t;
    const int* rr = rois + n * 4;
    int y0 = rr[0], x0 = rr[1], y1 = rr[2], x1 = rr[3];
    bool inb = ((unsigned)y0 < 11u) && ((unsigned)x0 < 11u) &&
               ((unsigned)y1 < 11u) && ((unsigned)x1 < 11u);
    int h = y1 - y0, ww = x1 - x0;
    int cat;
    if (inb && h == 4 && ww == 4) cat = 0;
    else if (inb && h == 8 && ww == 8) cat = 1;
    else if (inb && h == 4 && ww == 8) cat = 2;
    else if (inb && h == 6 && ww == 8) cat = 3;
    else { cat = 4; y0 = 1; x0 = 1; }
    union { unsigned char b[16]; uint4 q; } u;
    for (int cell = 0; cell < 16; ++cell)
      u.b[cell] = (unsigned char)cellmask(cat, y0, x0, cell >> 2, cell & 3);
    *(uint4*)(masks + n * 16) = u.q;
  } else {
    if (t < 128) {
      float acc = 0.f;
      for (int c = 0; c < 256; ++c) acc += b1[c] * w2[c * 128 + t];
      dval[t] = acc + b2[t];
    }
  }
}

// ---------------------------------------------------------------------------
// K2+K3 fused: D[(n*4+pq)][o] = sum_k x[n,k,pos(pq)]*W[k][o] + dval, then
// mask-based max-pool straight out of the accumulators -> pooled bf16.
// M-tile 64 (16 n), N=128, BK=64. grid 512 x 256. HBM-fetch-bound (268 MB).
__global__ __launch_bounds__(256) void k_dgemm_pool(
    const float* __restrict__ x,            // (8192, 512, 16) f32
    const unsigned short* __restrict__ Wt,  // (128, 512) bf16
    const float* __restrict__ dval, const float* __restrict__ b2,
    const unsigned char* __restrict__ masks,
    unsigned short* __restrict__ pooled)    // (8192, 16, 128) bf16
{
  __shared__ __align__(16) unsigned short As[64 * 64];
  __shared__ __align__(16) unsigned short Bs[128 * 64];
  const int t = threadIdx.x;
  const int bm = blockIdx.x;     // 0..511
  const int n0 = bm * 16;
  const int w = t >> 6, lane = t & 63;
  const int wm = (w >> 1) * 32, wn = (w & 1) * 64;
  const int lrow = lane & 15, lk = (lane >> 4) * 8;

  f32x4 acc[2][4];
  const f32x4 z = {0.f, 0.f, 0.f, 0.f};
  for (int i = 0; i < 2; ++i) for (int j = 0; j < 4; ++j) acc[i][j] = z;

  const int brow = t >> 1, bhalf = (t & 1) * 32;
  for (int k0 = 0; k0 < 512; k0 += 64) {
    // stage B: Wt rows (L2-resident), 2 threads/row x 64B
    {
      const unsigned short* gp = Wt + brow * 512 + k0 + bhalf;
      uint4 q0 = *(const uint4*)(gp + 0);
      uint4 q1 = *(const uint4*)(gp + 8);
      uint4 q2 = *(const uint4*)(gp + 16);
      uint4 q3 = *(const uint4*)(gp + 24);
      unsigned short* sp = Bs + brow * 64 + bhalf;
      *(uint4*)(sp + 0)  = q0;
      *(uint4*)(sp + 8)  = q1;
      *(uint4*)(sp + 16) = q2;
      *(uint4*)(sp + 24) = q3;
    }
    // stage A: gather x[n, k, {5,6,9,10}] via 2x float4, 4 (n,k) per thread
#pragma unroll
    for (int s = 0; s < 4; ++s) {
      int li = s * 256 + t;
      int nl = li >> 6;   // 0..15
      int k = li & 63;
      const float* gp = x + (size_t)(n0 + nl) * 8192 + (size_t)(k0 + k) * 16;
      float4 qa = *(const float4*)(gp + 4);
      float4 qb = *(const float4*)(gp + 8);
      unsigned short* sp = As + nl * 256 + k;
      sp[0]   = f2bf(qa.y);   // pos 5  -> pq0 (3,3)
      sp[64]  = f2bf(qa.z);   // pos 6  -> pq1 (3,7)
      sp[128] = f2bf(qb.y);   // pos 9  -> pq2 (7,3)
      sp[192] = f2bf(qb.z);   // pos 10 -> pq3 (7,7)
    }
    __syncthreads();
#pragma unroll
    for (int kk = 0; kk < 64; kk += 32) {
      bf16x8 a[2], b[4];
      for (int i = 0; i < 2; ++i)
        a[i] = *(const bf16x8*)&As[(wm + i * 16 + lrow) * 64 + kk + lk];
      for (int j = 0; j < 4; ++j)
        b[j] = *(const bf16x8*)&Bs[(wn + j * 16 + lrow) * 64 + kk + lk];
      for (int i = 0; i < 2; ++i)
        for (int j = 0; j < 4; ++j)
          acc[i][j] = __builtin_amdgcn_mfma_f32_16x16x32_bf16(a[i], b[j], acc[i][j], 0, 0, 0);
    }
    __syncthreads();
  }

  // fused pooling epilogue: lane holds all 4 pq of n in acc[i][j][0..3]
  const int lr = lane >> 4, lc = lane & 15;
  for (int i = 0; i < 2; ++i) {
    int n = n0 + (wm >> 2) + i * 4 + lr;
    uint4 mq = *(const uint4*)(masks + n * 16);
    const unsigned char* mb = (const unsigned char*)&mq;
    for (int j = 0; j < 4; ++j) {
      int o = wn + j * 16 + lc;
      float dv = dval[o], bv = b2[o];
      float d0 = acc[i][j][0] + dv, d1 = acc[i][j][1] + dv;
      float d2 = acc[i][j][2] + dv, d3 = acc[i][j][3] + dv;
      unsigned short* op = pooled + (size_t)n * 2048 + o;
#pragma unroll
      for (int cell = 0; cell < 16; ++cell) {
        int m = mb[cell];
        float v = (m & 1) ? bv : -FLT_MAX;
        if (m & 2)  v = fmaxf(v, dv);
        if (m & 4)  v = fmaxf(v, d0);
        if (m & 8)  v = fmaxf(v, d1);
        if (m & 16) v = fmaxf(v, d2);
        if (m & 32) v = fmaxf(v, d3);
        op[cell * 128] = f2bf(v);
      }
    }
  }
}

// ---------------------------------------------------------------------------
// K4: out = leaky( pooled(8192x2048) @ wlT(1024x2048)^T + bl ), m97 structure
// + XOR bank swizzle: LDS chunk (lane&7) of row r holds global chunk
// ((lane&7)^(r&7)); compute reads chunk (c ^ (r&7)). Rows spread across all
// 32 banks -> conflict-free ds_read_b128. grid (64,8) x 256.
__global__ __launch_bounds__(256) void k_gemm(
    const unsigned short* __restrict__ A,   // (8192, 2048) bf16
    const unsigned short* __restrict__ B,   // (1024, 2048) bf16
    const float* __restrict__ bias,         // (1024)
    float* __restrict__ C)                  // (8192, 1024) f32
{
  __shared__ __align__(16) unsigned short As[128 * 64];
  __shared__ __align__(16) unsigned short Bs[128 * 64];
  const int t = threadIdx.x;
  const int r0 = blockIdx.x * 128, c0 = blockIdx.y * 128;
  const int w = t >> 6, lane = t & 63;
  const int wm = (w >> 1) * 64, wn = (w & 1) * 64;
  const int lrow = lane & 15, lk = (lane >> 4) * 8;

  f32x4 acc[4][4];
  const f32x4 z = {0.f, 0.f, 0.f, 0.f};
  for (int i = 0; i < 4; ++i) for (int j = 0; j < 4; ++j) acc[i][j] = z;

  // wave w stages rows [w*32, w*32+32): 8 rows (1 KB) per DMA call, 4 calls;
  // lane reads the SWIZZLED global chunk so LDS dest stays base+lane*16.
  const int srow = lane >> 3;                      // 0..7
  const int scol = ((lane & 7) ^ srow) * 8;        // swizzled global chunk
  const unsigned short* Ag = A + (size_t)(r0 + w * 32 + srow) * 2048 + scol;
  const unsigned short* Bg = B + (size_t)(c0 + w * 32 + srow) * 2048 + scol;
  unsigned short* Asb = As + (w * 32) * 64;
  unsigned short* Bsb = Bs + (w * 32) * 64;

  // compute-side swizzled chunk offsets (lrow-dependent, loop-invariant)
  int sw[2][4];  // [kk/32][lk chunk] -> byte-chunk offset within row
#pragma unroll
  for (int kh = 0; kh < 2; ++kh)
#pragma unroll
    for (int q = 0; q < 4; ++q)
      sw[kh][q] = (((kh * 4 + q) ^ (lrow & 7)) * 8);

  const int myq = lk >> 3;  // this lane's chunk quarter (0..3)

  for (int k0 = 0; k0 < 2048; k0 += 64) {
#pragma unroll
    for (int c = 0; c < 4; ++c) {
      gl_lds16(Ag + (size_t)c * 8 * 2048 + k0, Asb + c * 8 * 64);
      gl_lds16(Bg + (size_t)c * 8 * 2048 + k0, Bsb + c * 8 * 64);
    }
    __syncthreads();
#pragma unroll
    for (int kk = 0; kk < 64; kk += 32) {
      const int off = sw[kk >> 5][myq];
      bf16x8 a[4], b[4];
      for (int i = 0; i < 4; ++i)
        a[i] = *(const bf16x8*)&As[(wm + i * 16 + lrow) * 64 + off];
      for (int j = 0; j < 4; ++j)
        b[j] = *(const bf16x8*)&Bs[(wn + j * 16 + lrow) * 64 + off];
      for (int i = 0; i < 4; ++i)
        for (int j = 0; j < 4; ++j)
          acc[i][j] = __builtin_amdgcn_mfma_f32_16x16x32_bf16(a[i], b[j], acc[i][j], 0, 0, 0);
    }
    __syncthreads();
  }

  const int rbase = r0 + wm + (lane >> 4) * 4;
  for (int j = 0; j < 4; ++j) {
    int col = c0 + wn + j * 16 + (lane & 15);
    float bv = bias[col];
    for (int i = 0; i < 4; ++i) {
      for (int r = 0; r < 4; ++r) {
        int row = rbase + i * 16 + r;
        float v = acc[i][j][r] + bv;
        C[(size_t)row * 1024 + col] = v > 0.f ? v : 0.01f * v;
      }
    }
  }
}

// ---------------------------------------------------------------------------
extern "C" void kernel_launch(void* const* d_in, const int* in_sizes, int n_in,
                              void* d_out, int out_size, void* d_ws, size_t ws_size,
                              hipStream_t stream) {
  const float* base_feat = (const float*)d_in[0];  // (32,256,512,4,4)
  const int*   rois      = (const int*)d_in[1];    // (8192,4)
  const float* w1        = (const float*)d_in[2];  // (512,256)
  const float* b1        = (const float*)d_in[3];  // (256)
  const float* w2        = (const float*)d_in[4];  // (256,128)
  const float* b2        = (const float*)d_in[5];  // (128)
  const float* wl        = (const float*)d_in[6];  // (2048,1024)
  const float* bl        = (const float*)d_in[7];  // (1024)
  float* out = (float*)d_out;                      // (8192,1024)

  char* ws = (char*)d_ws;
  // ws layout (bytes):
  //   Wt     bf16 128x512    @ 0          (131072)
  //   dval   f32  128        @ 131072     (512)
  //   masks  u8   8192x16    @ 131584     (131072)
  //   pooled bf16 8192x2048  @ 262656     (33554432)
  //   wlT    bf16 1024x2048  @ 33817088   (4194304)   total ~38 MB
  unsigned short* Wt     = (unsigned short*)(ws + 0);
  float*          dval   = (float*)(ws + 131072);
  unsigned char*  masks  = (unsigned char*)(ws + 131584);
  unsigned short* pooled = (unsigned short*)(ws + 262656);
  unsigned short* wlT    = (unsigned short*)(ws + 33817088);

  k_prep      <<<dim3(609),  dim3(256), 0, stream>>>(w1, b1, w2, b2, wl, rois,
                                                     Wt, dval, masks, wlT);
  k_dgemm_pool<<<dim3(512),  dim3(256), 0, stream>>>(base_feat, Wt, dval, b2, masks, pooled);
  k_gemm      <<<dim3(64, 8), dim3(256), 0, stream>>>(pooled, wlT, bl, out);
}